// Round 6
// baseline (457.632 us; speedup 1.0000x reference)
//
#include <hip/hip_runtime.h>
#include <math.h>

#define SCAN_B 1024
#define FILL_PASSES 8

typedef unsigned short u16;
typedef unsigned int u32;

// bf16 <-> f32 (bf16 = truncated f32; up-convert is an exact shift)
__device__ inline float bf2f(u16 u) {
    union { u32 i; float f; } c; c.i = ((u32)u) << 16; return c.f;
}
__device__ inline u16 f2bf(float f) {  // round-to-nearest-even
    union { float f; u32 i; } c; c.f = f;
    u32 r = c.i + 0x7FFFu + ((c.i >> 16) & 1u);
    return (u16)(r >> 16);
}

// ---------------- CSR build ----------------

__global__ void zero_counts_kernel(int* __restrict__ c, int n) {
    int i = blockIdx.x * blockDim.x + threadIdx.x;
    if (i < n) c[i] = 0;
}

__global__ void hist_kernel(const int* __restrict__ dst, int* __restrict__ counts, int e) {
    int i = blockIdx.x * blockDim.x + threadIdx.x;
    if (i < e) atomicAdd(&counts[dst[i]], 1);
}

// block-local exclusive scan of counts -> rowptr ; block totals -> bsums ; dis fused
__global__ void scan1_kernel(const int* __restrict__ counts, int* __restrict__ rowptr,
                             int* __restrict__ bsums, float* __restrict__ dis, int n) {
    __shared__ int tmp[SCAN_B];
    int tid = threadIdx.x;
    int i = blockIdx.x * SCAN_B + tid;
    int v = (i < n) ? counts[i] : 0;
    if (i < n) dis[i] = rsqrtf((float)v + 1.0f);   // self-loop included
    tmp[tid] = v;
    __syncthreads();
    #pragma unroll
    for (int off = 1; off < SCAN_B; off <<= 1) {
        int t = (tid >= off) ? tmp[tid - off] : 0;
        __syncthreads();
        tmp[tid] += t;
        __syncthreads();
    }
    if (i < n) rowptr[i] = tmp[tid] - v;           // exclusive within block
    if (tid == SCAN_B - 1) bsums[blockIdx.x] = tmp[tid];
}

// single-block exclusive scan of bsums (nb <= SCAN_B)
__global__ void scan2_kernel(int* __restrict__ bsums, int nb) {
    __shared__ int tmp[SCAN_B];
    int tid = threadIdx.x;
    int v = (tid < nb) ? bsums[tid] : 0;
    tmp[tid] = v;
    __syncthreads();
    #pragma unroll
    for (int off = 1; off < SCAN_B; off <<= 1) {
        int t = (tid >= off) ? tmp[tid - off] : 0;
        __syncthreads();
        tmp[tid] += t;
        __syncthreads();
    }
    if (tid < nb) bsums[tid] = tmp[tid] - v;
}

// add block offsets; copy to fill-cursor array; write rowptr[n]=e
__global__ void scan3_kernel(int* __restrict__ rowptr, int* __restrict__ next,
                             const int* __restrict__ bsums, int n, int e) {
    int i = blockIdx.x * blockDim.x + threadIdx.x;
    if (i < n) {
        int r = rowptr[i] + bsums[i / SCAN_B];
        rowptr[i] = r;
        next[i] = r;
    }
    if (i == 0) rowptr[n] = e;
}

// bucket-fill, dst-range filtered: only edges with dst in [lo,hi) are written.
// Each pass's output slice (~e/8 records, ~1.6 MB) stays L2-resident so the
// ~16 records per 64B sector merge before write-back (round-5 post-mortem:
// single-pass fill wrote 101 MB = 64 B per edge, no merging).
__global__ void fill_range_kernel(const int* __restrict__ src, const int* __restrict__ dst,
                                  int* __restrict__ next, const float* __restrict__ dis,
                                  int2* __restrict__ erec, int e, int lo, int hi) {
    int i = blockIdx.x * blockDim.x + threadIdx.x;
    if (i < e) {
        int d = dst[i];
        if (d >= lo && d < hi) {
            int s = src[i];
            float w = dis[s] * dis[d];
            int pos = atomicAdd(&next[d], 1);
            erec[pos] = make_int2(s, __float_as_int(w));
        }
    }
}

// ---------------- register-tiled GEMM: Y[n,OUT] = X[n,IN] @ W[IN,OUT] (+bias) ----------------
// block = 256 threads -> 64 rows x 64 (padded) cols; thread = 4x4 tile.
// k-loop kept at unroll 1 (round-3 post-mortem: full unroll -> 256 VGPR spill).

__device__ inline float4 load4(const float* p) { return *(const float4*)p; }
__device__ inline float4 load4(const u16* p) {
    ushort4 u = *(const ushort4*)p;
    return make_float4(bf2f(u.x), bf2f(u.y), bf2f(u.z), bf2f(u.w));
}

template<typename XT, typename YT, int IN_F, int OUT_F, bool BIAS>
__global__ __launch_bounds__(256) void gemm_tile_kernel(const XT* __restrict__ X,
                                                        const float* __restrict__ W,
                                                        const float* __restrict__ bias,
                                                        YT* __restrict__ Y, int n) {
    constexpr int PC = 64;  // padded col count
    __shared__ float Wl[IN_F * PC];
    int tid = threadIdx.x;
    for (int idx = tid; idx < IN_F * PC; idx += 256) {
        int k = idx / PC, c = idx % PC;
        Wl[idx] = (c < OUT_F) ? W[k * OUT_F + c] : 0.f;
    }
    __syncthreads();
    int tx = tid & 15;   // col group (4 cols)
    int ty = tid >> 4;   // row group (4 rows)
    int r0 = blockIdx.x * 64 + ty * 4;
    int c0 = tx * 4;
    // clamped row pointers: always in-bounds, no per-iteration select
    const XT* xr[4];
    #pragma unroll
    for (int i = 0; i < 4; ++i) {
        int r = r0 + i;
        if (r >= n) r = n - 1;
        xr[i] = X + (size_t)r * IN_F;
    }
    float acc[4][4] = {};
    const float4* Wv = (const float4*)Wl;  // index: k*16 + tx
    #pragma unroll 1
    for (int k = 0; k < IN_F; k += 4) {
        float4 xv[4];
        #pragma unroll
        for (int i = 0; i < 4; ++i) xv[i] = load4(xr[i] + k);
        #pragma unroll
        for (int j = 0; j < 4; ++j) {
            float4 wv = Wv[(k + j) * 16 + tx];
            #pragma unroll
            for (int i = 0; i < 4; ++i) {
                float xs = (j == 0) ? xv[i].x : (j == 1) ? xv[i].y : (j == 2) ? xv[i].z : xv[i].w;
                acc[i][0] = fmaf(xs, wv.x, acc[i][0]);
                acc[i][1] = fmaf(xs, wv.y, acc[i][1]);
                acc[i][2] = fmaf(xs, wv.z, acc[i][2]);
                acc[i][3] = fmaf(xs, wv.w, acc[i][3]);
            }
        }
    }
    if (c0 < OUT_F) {
        float4 bb = make_float4(0.f, 0.f, 0.f, 0.f);
        if (BIAS) bb = *(const float4*)(bias + c0);
        #pragma unroll
        for (int i = 0; i < 4; ++i) {
            int r = r0 + i;
            if (r < n) {
                if constexpr (sizeof(YT) == 2) {
                    ushort4 o;
                    o.x = f2bf(acc[i][0] + bb.x);
                    o.y = f2bf(acc[i][1] + bb.y);
                    o.z = f2bf(acc[i][2] + bb.z);
                    o.w = f2bf(acc[i][3] + bb.w);
                    *(ushort4*)(Y + (size_t)r * OUT_F + c0) = o;
                } else {
                    float4 o = make_float4(acc[i][0] + bb.x, acc[i][1] + bb.y,
                                           acc[i][2] + bb.z, acc[i][3] + bb.w);
                    *(float4*)(Y + (size_t)r * OUT_F + c0) = o;
                }
            }
        }
    }
}

// ---------------- gather aggregation (one 64-lane wave per node, 64 bf16 cols) ----------------
// out[i,c] = act( dis_i^2 * v[i,c] + sum_j wn_j * v[src_j, c]  (+ b[c]) )
// unroll 8 for memory-level parallelism on the random 128B row gathers.

template<bool RELU_BIAS>
__global__ void gather64_kernel(const u16* __restrict__ v, const int* __restrict__ rowptr,
                                const int2* __restrict__ erec, const float* __restrict__ dis,
                                const float* __restrict__ b, u16* __restrict__ out, int n) {
    int wid = __builtin_amdgcn_readfirstlane((blockIdx.x * blockDim.x + threadIdx.x) >> 6);
    int lane = threadIdx.x & 63;
    if (wid >= n) return;  // wave-uniform
    int beg = __builtin_amdgcn_readfirstlane(rowptr[wid]);
    int end = __builtin_amdgcn_readfirstlane(rowptr[wid + 1]);
    float di = dis[wid];
    float acc = bf2f(v[(size_t)wid * 64 + lane]) * (di * di);
    int j = beg;
    for (; j + 8 <= end; j += 8) {
        int2 er[8];
        #pragma unroll
        for (int q = 0; q < 8; ++q) er[q] = erec[j + q];
        float vv[8];
        #pragma unroll
        for (int q = 0; q < 8; ++q) vv[q] = bf2f(v[(size_t)er[q].x * 64 + lane]);
        #pragma unroll
        for (int q = 0; q < 8; ++q) acc = fmaf(vv[q], __int_as_float(er[q].y), acc);
    }
    for (; j + 4 <= end; j += 4) {
        int2 e0 = erec[j], e1 = erec[j + 1], e2 = erec[j + 2], e3 = erec[j + 3];
        float v0 = bf2f(v[(size_t)e0.x * 64 + lane]);
        float v1 = bf2f(v[(size_t)e1.x * 64 + lane]);
        float v2 = bf2f(v[(size_t)e2.x * 64 + lane]);
        float v3 = bf2f(v[(size_t)e3.x * 64 + lane]);
        acc = fmaf(v0, __int_as_float(e0.y), acc);
        acc = fmaf(v1, __int_as_float(e1.y), acc);
        acc = fmaf(v2, __int_as_float(e2.y), acc);
        acc = fmaf(v3, __int_as_float(e3.y), acc);
    }
    for (; j < end; ++j) {
        int2 ee = erec[j];
        acc = fmaf(bf2f(v[(size_t)ee.x * 64 + lane]), __int_as_float(ee.y), acc);
    }
    if (RELU_BIAS) acc = fmaxf(acc + b[lane], 0.f);
    out[(size_t)wid * 64 + lane] = f2bf(acc);
}

// out[i,:] = log_softmax(z[i,:]) over 40 cols; one wave per row
__global__ void logsoftmax_kernel(const float* __restrict__ z, float* __restrict__ out, int n) {
    int wid = (blockIdx.x * blockDim.x + threadIdx.x) >> 6;
    int lane = threadIdx.x & 63;
    if (wid >= n) return;
    float zz = (lane < 40) ? z[(size_t)wid * 40 + lane] : -INFINITY;
    float v = zz;
    #pragma unroll
    for (int off = 32; off > 0; off >>= 1) v = fmaxf(v, __shfl_xor(v, off));
    float ex = (lane < 40) ? expf(zz - v) : 0.f;
    float s = ex;
    #pragma unroll
    for (int off = 32; off > 0; off >>= 1) s += __shfl_xor(s, off);
    float ls = logf(s);
    if (lane < 40) out[(size_t)wid * 40 + lane] = zz - v - ls;
}

// ---------------- launch ----------------

extern "C" void kernel_launch(void* const* d_in, const int* in_sizes, int n_in,
                              void* d_out, int out_size, void* d_ws, size_t ws_size,
                              hipStream_t stream) {
    const float* x  = (const float*)d_in[0];
    const int*   ei = (const int*)d_in[1];   // [2, E] int32
    const float* W1 = (const float*)d_in[2]; // [128, 64]
    const float* b1 = (const float*)d_in[3]; // [64]
    const float* W2 = (const float*)d_in[4]; // [64, 40]
    const float* b2 = (const float*)d_in[5]; // [40]
    float* out = (float*)d_out;              // [n, 40]

    const int n = in_sizes[0] / 128;
    const int e = in_sizes[1] / 2;
    const int* src = ei;
    const int* dst = ei + e;

    // workspace layout (8B-aligned blocks):
    //   erec[e] int2 | dis[n] f32 | counts/next[n] i32 | rowptr[n+2] i32 |
    //   bsums[1024] i32 | A[n*64] bf16 | B[n*64] bf16 | Z[n*40] f32    (~56 MB)
    int2* erec  = (int2*)d_ws;
    float* dis  = (float*)(erec + e);
    int* counts = (int*)(dis + n);           // reused as fill cursor 'next'
    int* rowptr = counts + n;
    int* bsums  = rowptr + (n + 2);          // +2 keeps later blocks 8B-aligned
    u16* A      = (u16*)(bsums + SCAN_B);    // xw1 (bf16), then G (aggregated H)
    u16* B      = A + (size_t)n * 64;        // H (bf16)
    float* Z    = (float*)(B + (size_t)n * 64);  // logits (n x 40, f32)

    const int T = 256;
    const int nb = (n + SCAN_B - 1) / SCAN_B;

    // --- CSR build + normalization ---
    zero_counts_kernel<<<(n + T - 1) / T, T, 0, stream>>>(counts, n);
    hist_kernel<<<(e + T - 1) / T, T, 0, stream>>>(dst, counts, e);
    scan1_kernel<<<nb, SCAN_B, 0, stream>>>(counts, rowptr, bsums, dis, n);
    scan2_kernel<<<1, SCAN_B, 0, stream>>>(bsums, nb);
    scan3_kernel<<<(n + T - 1) / T, T, 0, stream>>>(rowptr, counts, bsums, n, e);
    {
        int step = (n + FILL_PASSES - 1) / FILL_PASSES;
        for (int p = 0; p < FILL_PASSES; ++p) {
            int lo = p * step;
            int hi = (p == FILL_PASSES - 1) ? n : lo + step;
            fill_range_kernel<<<(e + T - 1) / T, T, 0, stream>>>(src, dst, counts, dis, erec, e, lo, hi);
        }
    }

    // --- layer 1: xw1 = x@W1 (bf16) ; H = relu(aggregate(xw1) + b1) (bf16) ---
    gemm_tile_kernel<float, u16, 128, 64, false>
        <<<(n + 63) / 64, 256, 0, stream>>>(x, W1, nullptr, A, n);
    gather64_kernel<true><<<(n * 64 + T - 1) / T, T, 0, stream>>>(A, rowptr, erec, dis, b1, B, n);

    // --- layer 2 (reassociated): G = aggregate(H) (bf16); Z = G@W2 + b2; out = log_softmax(Z) ---
    gather64_kernel<false><<<(n * 64 + T - 1) / T, T, 0, stream>>>(B, rowptr, erec, dis, nullptr, A, n);
    gemm_tile_kernel<u16, float, 64, 40, true>
        <<<(n + 63) / 64, 256, 0, stream>>>(A, W2, b2, Z, n);
    logsoftmax_kernel<<<(n * 64 + T - 1) / T, T, 0, stream>>>(Z, out, n);
}